// Round 1
// baseline (817.153 us; speedup 1.0000x reference)
//
#include <hip/hip_runtime.h>
#include <cmath>

// Problem constants
#define B_    4
#define T_    1000000
#define E_    8
#define C_    128
#define NCH   512        // fused conv output channels (both branches, 2*2C)
#define KK    4096       // GEMM K = E * kernel (8*512); windows are contiguous rows
#define TOUT  1953       // (1e6 - 512)/512 + 1
#define NT2   31         // ceil(1953/64) tiles of 64 along t

__device__ __forceinline__ float sigmoidf_(float v) { return 1.f / (1.f + __expf(-v)); }

// ---------------------------------------------------------------------------
// Kernel 0: rearrange conv weights (o,e,k) -> Wt[n][k*8+e], n permuted so GLU
// pairs (a-chan c, gate-chan c+128) sit at adjacent n = br*256 + c*2 + {0,1}.
// Also gather permuted bias.
__global__ void prep_weights(const float* __restrict__ wc, const float* __restrict__ bc,
                             const float* __restrict__ wm, const float* __restrict__ bm,
                             float* __restrict__ Wt, float* __restrict__ bias_t) {
  int n = blockIdx.x;              // 0..511
  int br = n >> 8, r = n & 255, p = r & 1, c = r >> 1;
  int o = p * 128 + c;             // original channel in (256,8,512)
  const float* ws = br ? wm : wc;
  const float* bs = br ? bm : bc;
  for (int idx = threadIdx.x; idx < KK; idx += blockDim.x) {
    int k = idx >> 3, e = idx & 7;
    Wt[(size_t)n * KK + idx] = ws[(size_t)o * KK + e * 512 + k];
  }
  if (threadIdx.x == 0) bias_t[n] = bs[o];
}

// ---------------------------------------------------------------------------
// Kernel 1: the big GEMM + bias + GLU epilogue.
// A: (per b) rows t<1953, row ptr = x + b*8e6 + t*4096 (contiguous window)
// B: Wt (512 x 4096). Tile 128x128, BK=16, 256 threads, 8x8 micro-tile
// (split rows/cols {q*4..q*4+3} U {64+q*4..} for conflict-free LDS b128 reads).
__global__ __launch_bounds__(256) void conv_glu_gemm(
    const float* __restrict__ x, const float* __restrict__ Wt,
    const float* __restrict__ bias_t, float* __restrict__ u) {
  __shared__ float As[16][128];
  __shared__ float Bs[16][128];
  const int tid = threadIdx.x;
  const int n0 = blockIdx.x * 128;   // 0..3
  const int t0 = blockIdx.y * 128;   // 0..15
  const int b  = blockIdx.z;
  const int ty = tid >> 4, tx = tid & 15;

  float acc[8][8];
#pragma unroll
  for (int i = 0; i < 8; ++i)
#pragma unroll
    for (int j = 0; j < 8; ++j) acc[i][j] = 0.f;

  const int srow = tid >> 1;          // 0..127
  const int skq  = (tid & 1) << 3;    // 0 or 8
  const bool avalid = (t0 + srow) < TOUT;
  const float* aptr = x + (size_t)b * ((size_t)T_ * E_) + (size_t)(t0 + srow) * KK + skq;
  const float* bptr = Wt + (size_t)(n0 + srow) * KK + skq;

  for (int k0 = 0; k0 < KK; k0 += 16) {
    float4 a0 = {0.f,0.f,0.f,0.f}, a1 = {0.f,0.f,0.f,0.f};
    if (avalid) {
      a0 = *(const float4*)(aptr + k0);
      a1 = *(const float4*)(aptr + k0 + 4);
    }
    float4 b0 = *(const float4*)(bptr + k0);
    float4 b1 = *(const float4*)(bptr + k0 + 4);
    __syncthreads();
    As[skq+0][srow] = a0.x; As[skq+1][srow] = a0.y;
    As[skq+2][srow] = a0.z; As[skq+3][srow] = a0.w;
    As[skq+4][srow] = a1.x; As[skq+5][srow] = a1.y;
    As[skq+6][srow] = a1.z; As[skq+7][srow] = a1.w;
    Bs[skq+0][srow] = b0.x; Bs[skq+1][srow] = b0.y;
    Bs[skq+2][srow] = b0.z; Bs[skq+3][srow] = b0.w;
    Bs[skq+4][srow] = b1.x; Bs[skq+5][srow] = b1.y;
    Bs[skq+6][srow] = b1.z; Bs[skq+7][srow] = b1.w;
    __syncthreads();
#pragma unroll
    for (int kk = 0; kk < 16; ++kk) {
      float av[8], bv[8];
      float4 v;
      v = *(const float4*)&As[kk][ty*4];      av[0]=v.x; av[1]=v.y; av[2]=v.z; av[3]=v.w;
      v = *(const float4*)&As[kk][64+ty*4];   av[4]=v.x; av[5]=v.y; av[6]=v.z; av[7]=v.w;
      v = *(const float4*)&Bs[kk][tx*4];      bv[0]=v.x; bv[1]=v.y; bv[2]=v.z; bv[3]=v.w;
      v = *(const float4*)&Bs[kk][64+tx*4];   bv[4]=v.x; bv[5]=v.y; bv[6]=v.z; bv[7]=v.w;
#pragma unroll
      for (int i = 0; i < 8; ++i)
#pragma unroll
        for (int j = 0; j < 8; ++j) acc[i][j] = fmaf(av[i], bv[j], acc[i][j]);
    }
  }

  // Epilogue: bias + GLU (pairs are adjacent n). u layout: [br][b][c][t]
  float biasv[8];
#pragma unroll
  for (int j = 0; j < 8; ++j) {
    int n = n0 + ((j < 4) ? (tx*4 + j) : (64 + tx*4 + (j - 4)));
    biasv[j] = bias_t[n];
  }
#pragma unroll
  for (int i = 0; i < 8; ++i) {
    int t = t0 + ((i < 4) ? (ty*4 + i) : (64 + ty*4 + (i - 4)));
    if (t >= TOUT) continue;
#pragma unroll
    for (int jp = 0; jp < 4; ++jp) {
      int j = (jp < 2) ? (jp * 2) : (4 + (jp - 2) * 2);   // 0,2,4,6
      int n = n0 + ((j < 4) ? (tx*4 + j) : (64 + tx*4 + (j - 4)));
      float va = acc[i][j]   + biasv[j];
      float vg = acc[i][j+1] + biasv[j+1];
      float uval = va * sigmoidf_(vg);
      int br = n >> 8, c = (n & 255) >> 1;
      u[((size_t)(br * 4 + b) * 128 + c) * TOUT + t] = uval;
    }
  }
}

// ---------------------------------------------------------------------------
// Kernel 2: 1x1 share conv + leaky. Per (branch, b, t-tile of 64).
// br==1: store h_main; br==0: per-tile max over t -> gct_part.
__global__ __launch_bounds__(256) void share_act(
    const float* __restrict__ u,
    const float* __restrict__ wsc, const float* __restrict__ bsc,
    const float* __restrict__ wsm, const float* __restrict__ bsm,
    float* __restrict__ hmain, float* __restrict__ gct_part) {
  __shared__ float Wl[128 * 132];   // Wl[cp*132 + cout] = ws[cout, cp]
  __shared__ float ul[128 * 68];    // ul[cp*68 + t]
  const int tid  = threadIdx.x;
  const int tile = blockIdx.x;      // 0..30
  const int b    = blockIdx.y;
  const int br   = blockIdx.z;
  const int t0   = tile * 64;
  const float* ws = br ? wsm : wsc;
  const float* bs = br ? bsm : bsc;

  for (int g = tid; g < 16384; g += 256) {
    int co = g >> 7, cp = g & 127;
    Wl[cp * 132 + co] = ws[g];
  }
  const size_t ubase = (size_t)(br * 4 + b) * 128 * (size_t)TOUT;
  for (int g = tid; g < 8192; g += 256) {
    int cp = g >> 6, t = g & 63;
    float v = 0.f;
    if (t0 + t < TOUT) v = u[ubase + (size_t)cp * TOUT + t0 + t];
    ul[cp * 68 + t] = v;
  }
  __syncthreads();

  const int ty = tid >> 4, tx = tid & 15;  // c-groups x t-groups
  float acc[8][4];
#pragma unroll
  for (int i = 0; i < 8; ++i)
#pragma unroll
    for (int j = 0; j < 4; ++j) acc[i][j] = 0.f;

  for (int cp = 0; cp < 128; ++cp) {
    float4 a0 = *(const float4*)&Wl[cp*132 + ty*4];
    float4 a1 = *(const float4*)&Wl[cp*132 + 64 + ty*4];
    float4 b4 = *(const float4*)&ul[cp*68 + tx*4];
    float av[8] = {a0.x,a0.y,a0.z,a0.w,a1.x,a1.y,a1.z,a1.w};
    float bv[4] = {b4.x,b4.y,b4.z,b4.w};
#pragma unroll
    for (int i = 0; i < 8; ++i)
#pragma unroll
      for (int j = 0; j < 4; ++j) acc[i][j] = fmaf(av[i], bv[j], acc[i][j]);
  }

  float mloc[8];
#pragma unroll
  for (int i = 0; i < 8; ++i) mloc[i] = -INFINITY;
#pragma unroll
  for (int i = 0; i < 8; ++i) {
    int c = (i < 4) ? (ty*4 + i) : (64 + ty*4 + (i - 4));
    float bias = bs[c];
#pragma unroll
    for (int j = 0; j < 4; ++j) {
      int t = t0 + tx*4 + j;
      if (t >= TOUT) continue;
      float v = acc[i][j] + bias;
      v = (v >= 0.f) ? v : 0.01f * v;
      if (br == 1) {
        hmain[((size_t)b * 128 + c) * TOUT + t] = v;
      } else {
        mloc[i] = fmaxf(mloc[i], v);
      }
    }
  }
  if (br == 0) {
    __syncthreads();               // done reading ul; reuse as reduction buffer
    float* red = ul;               // 128*16 region
#pragma unroll
    for (int i = 0; i < 8; ++i) {
      int c = (i < 4) ? (ty*4 + i) : (64 + ty*4 + (i - 4));
      red[c * 16 + tx] = mloc[i];
    }
    __syncthreads();
    if (tid < 128) {
      float m = -INFINITY;
#pragma unroll
      for (int k = 0; k < 16; ++k) m = fmaxf(m, red[tid * 16 + k]);
      gct_part[((size_t)b * 128 + tid) * NT2 + tile] = m;
    }
  }
}

// ---------------------------------------------------------------------------
// Kernel 3: gct = max over tiles; q = tanh(gct @ Wp^T + bp). One block per b.
__global__ void gct_q(const float* __restrict__ gct_part, const float* __restrict__ wp,
                      const float* __restrict__ bp, float* __restrict__ q) {
  int b = blockIdx.x, tid = threadIdx.x;   // 128 threads
  __shared__ float g[128];
  float m = -INFINITY;
  for (int tl = 0; tl < NT2; ++tl) m = fmaxf(m, gct_part[((size_t)b * 128 + tid) * NT2 + tl]);
  g[tid] = m;
  __syncthreads();
  float s = bp[tid];
  for (int c = 0; c < 128; ++c) s = fmaf(g[c], wp[tid * 128 + c], s);
  q[b * 128 + tid] = tanhf(s);
}

// ---------------------------------------------------------------------------
// Kernel 4: gate[t] = sigmoid(sum_c h*q); out_part = per-tile max_t h*gate.
__global__ __launch_bounds__(256) void gate_max(
    const float* __restrict__ hmain, const float* __restrict__ q,
    float* __restrict__ out_part) {
  __shared__ float hl[128 * 68];
  __shared__ float ql[128];
  __shared__ float red[256];
  __shared__ float gl[64];
  int tid = threadIdx.x, tile = blockIdx.x, b = blockIdx.y;
  int t0 = tile * 64;
  for (int g = tid; g < 8192; g += 256) {
    int c = g >> 6, t = g & 63;
    hl[c * 68 + t] = (t0 + t < TOUT) ? hmain[((size_t)b * 128 + c) * TOUT + t0 + t] : 0.f;
  }
  if (tid < 128) ql[tid] = q[b * 128 + tid];
  __syncthreads();
  {
    int t = tid & 63, cy = tid >> 6;
    float s = 0.f;
#pragma unroll
    for (int cc = 0; cc < 32; ++cc) s = fmaf(hl[(cy * 32 + cc) * 68 + t], ql[cy * 32 + cc], s);
    red[cy * 64 + t] = s;
  }
  __syncthreads();
  if (tid < 64) {
    float s = red[tid] + red[64 + tid] + red[128 + tid] + red[192 + tid];
    gl[tid] = sigmoidf_(s);
  }
  __syncthreads();
  {
    int c = tid >> 1, th = tid & 1;
    float m = -INFINITY;
#pragma unroll
    for (int tt = 0; tt < 32; ++tt) {
      int t = th * 32 + tt;
      if (t0 + t < TOUT) m = fmaxf(m, hl[c * 68 + t] * gl[t]);
    }
    red[c * 2 + th] = m;
  }
  __syncthreads();
  if (tid < 128) out_part[((size_t)b * 128 + tid) * NT2 + tile] = fmaxf(red[tid * 2], red[tid * 2 + 1]);
}

// ---------------------------------------------------------------------------
// Kernel 5: final max over tiles -> d_out (B,C) row-major.
__global__ void final_max(const float* __restrict__ out_part, float* __restrict__ out) {
  int idx = blockIdx.x * 256 + threadIdx.x;
  if (idx < 512) {
    float m = -INFINITY;
    for (int tl = 0; tl < NT2; ++tl) m = fmaxf(m, out_part[(size_t)idx * NT2 + tl]);
    out[idx] = m;
  }
}

// ---------------------------------------------------------------------------
extern "C" void kernel_launch(void* const* d_in, const int* in_sizes, int n_in,
                              void* d_out, int out_size, void* d_ws, size_t ws_size,
                              hipStream_t stream) {
  const float* x      = (const float*)d_in[0];
  const float* ctx_w  = (const float*)d_in[1];
  const float* ctx_b  = (const float*)d_in[2];
  const float* ctx_sw = (const float*)d_in[3];
  const float* ctx_sb = (const float*)d_in[4];
  const float* main_w = (const float*)d_in[5];
  const float* main_b = (const float*)d_in[6];
  const float* main_sw= (const float*)d_in[7];
  const float* main_sb= (const float*)d_in[8];
  const float* gp_w   = (const float*)d_in[9];
  const float* gp_b   = (const float*)d_in[10];

  float* ws       = (float*)d_ws;
  float* Wt       = ws;                                   // 512*4096
  float* bias_t   = Wt + (size_t)NCH * KK;                // 512
  float* u        = bias_t + NCH;                         // 2*4*128*1953
  float* hmain    = u + (size_t)2 * B_ * C_ * TOUT;       // 4*128*1953
  float* gct_part = hmain + (size_t)B_ * C_ * TOUT;       // 4*128*31
  float* q        = gct_part + (size_t)B_ * C_ * NT2;     // 512
  float* out_part = q + B_ * C_;                          // 4*128*31

  prep_weights<<<NCH, 256, 0, stream>>>(ctx_w, ctx_b, main_w, main_b, Wt, bias_t);
  conv_glu_gemm<<<dim3(4, 16, B_), 256, 0, stream>>>(x, Wt, bias_t, u);
  share_act<<<dim3(NT2, B_, 2), 256, 0, stream>>>(u, ctx_sw, ctx_sb, main_sw, main_sb,
                                                  hmain, gct_part);
  gct_q<<<B_, 128, 0, stream>>>(gct_part, gp_w, gp_b, q);
  gate_max<<<dim3(NT2, B_), 256, 0, stream>>>(hmain, q, out_part);
  final_max<<<2, 256, 0, stream>>>(out_part, (float*)d_out);
}

// Round 2
// 354.296 us; speedup vs baseline: 2.3064x; 2.3064x over previous
//
#include <hip/hip_runtime.h>
#include <hip/hip_bf16.h>
#include <cmath>

// Problem constants
#define B_    4
#define T_    1000000
#define E_    8
#define C_    128
#define NCH   512        // fused conv output channels (both branches, 2*256)
#define KK    4096       // GEMM K = E * kernel (8*512); windows are contiguous rows
#define TOUT  1953       // (1e6 - 512)/512 + 1
#define TP    1956       // padded t stride (mult of 4) for aligned float4 stores
#define TPAD  2048       // padded rows per batch in xb (zero-filled past 1952)
#define NT2   31         // ceil(1953/64) tiles of 64 along t

typedef __attribute__((ext_vector_type(8))) short bf16x8;   // 8 bf16 = 4 VGPRs
typedef __attribute__((ext_vector_type(4))) float f32x4;

__device__ __forceinline__ float sigmoidf_(float v) { return 1.f / (1.f + __expf(-v)); }

__device__ __forceinline__ void gl2lds16(const void* g, void* l) {
  __builtin_amdgcn_global_load_lds((const __attribute__((address_space(1))) void*)g,
                                   (__attribute__((address_space(3))) void*)l, 16, 0, 0);
}

// ---------------------------------------------------------------------------
// Kernel A: x fp32 -> bf16, padded to TPAD rows of 4096 per batch (zeros past
// valid data). Per-b padded region is exactly 2^23 elements.
__global__ __launch_bounds__(256) void convert_x(const float* __restrict__ x,
                                                 __hip_bfloat16* __restrict__ xb) {
  size_t gid = (size_t)blockIdx.x * 256 + threadIdx.x;
  size_t idx8 = gid * 8;                  // element index in padded [4][2^23]
  size_t b = idx8 >> 23;
  size_t rem = idx8 & ((1ull << 23) - 1);
  union { __hip_bfloat16 h[8]; uint4 u; } o;
  if (rem < (size_t)TOUT * KK) {          // 7,999,488, divisible by 8
    const float* src = x + b * 8000000ull + rem;
    float4 f0 = *(const float4*)(src);
    float4 f1 = *(const float4*)(src + 4);
    o.h[0] = __float2bfloat16(f0.x); o.h[1] = __float2bfloat16(f0.y);
    o.h[2] = __float2bfloat16(f0.z); o.h[3] = __float2bfloat16(f0.w);
    o.h[4] = __float2bfloat16(f1.x); o.h[5] = __float2bfloat16(f1.y);
    o.h[6] = __float2bfloat16(f1.z); o.h[7] = __float2bfloat16(f1.w);
  } else {
    o.u = make_uint4(0, 0, 0, 0);
  }
  *(uint4*)(xb + idx8) = o.u;
}

// ---------------------------------------------------------------------------
// Kernel B: weights (o,e,kpos) -> bf16 Wtb[n][kpos*8+e], n = br*256 + o
// (identity channel order; GLU pairing handled downstream). LDS transpose so
// both global read and write are coalesced. bias_t same order (fp32).
__global__ __launch_bounds__(256) void prep_w(
    const float* __restrict__ wc, const float* __restrict__ bc,
    const float* __restrict__ wm, const float* __restrict__ bm,
    __hip_bfloat16* __restrict__ Wtb, float* __restrict__ bias_t) {
  __shared__ float row[KK];
  int n = blockIdx.x;                 // 0..511
  int br = n >> 8, o = n & 255;
  const float* wsrc = (br ? wm : wc) + (size_t)o * KK;
  for (int i = threadIdx.x; i < KK; i += 256) row[i] = wsrc[i];   // [e][kpos]
  __syncthreads();
  for (int i = threadIdx.x; i < KK; i += 256) {
    int kpos = i >> 3, e = i & 7;
    Wtb[(size_t)n * KK + i] = __float2bfloat16(row[e * 512 + kpos]);
  }
  if (threadIdx.x == 0) bias_t[n] = (br ? bm : bc)[o];
}

// ---------------------------------------------------------------------------
// Kernel C: bf16 MFMA GEMM. C[t,n] = sum_k A[t,k] * W[n,k], tile 128x128,
// BK=32, 256 threads = 4 waves in 2x2, each wave 64x64 via 4x4 of
// mfma_f32_16x16x32_bf16. global_load_lds width-16 staging (m97 structure).
// Epilogue: + bias, store fp32 to u2[n][b][TP].
__global__ __launch_bounds__(256) void mfma_gemm(
    const __hip_bfloat16* __restrict__ xb, const __hip_bfloat16* __restrict__ Wtb,
    const float* __restrict__ bias_t, float* __restrict__ u2) {
  __shared__ __hip_bfloat16 As[128 * 32];
  __shared__ __hip_bfloat16 Bs[128 * 32];
  const int tid  = threadIdx.x;
  const int lane = tid & 63, wave = tid >> 6;
  const int wm = wave >> 1, wn = wave & 1;
  const int n0 = blockIdx.x * 128;
  const int t0 = blockIdx.y * 128;
  const int b  = blockIdx.z;

  // Staging: chunk l in [0,512) of 16B; l = it*256 + tid; r=l>>2, q=l&3.
  const int r0 = tid >> 2;            // 0..63 (it0), +64 (it1)
  const int q8 = (tid & 3) * 8;
  const __hip_bfloat16* aS = xb + ((size_t)b * TPAD + (t0 + r0)) * KK + q8;
  const __hip_bfloat16* bS = Wtb + (size_t)(n0 + r0) * KK + q8;
  __hip_bfloat16* aD0 = As + (wave * 64) * 8;
  __hip_bfloat16* aD1 = As + (256 + wave * 64) * 8;
  __hip_bfloat16* bD0 = Bs + (wave * 64) * 8;
  __hip_bfloat16* bD1 = Bs + (256 + wave * 64) * 8;

  f32x4 acc[4][4];
#pragma unroll
  for (int i = 0; i < 4; ++i)
#pragma unroll
    for (int j = 0; j < 4; ++j) acc[i][j] = (f32x4)(0.0f);

  const int mrow = lane & 15;         // row within 16x16 frag
  const int kq   = (lane >> 4) * 8;   // k-quad offset

  for (int k0 = 0; k0 < KK; k0 += 32) {
    __syncthreads();                  // previous iter's ds_reads done
    gl2lds16(aS + k0, aD0);
    gl2lds16(aS + 64 * KK + k0, aD1);
    gl2lds16(bS + k0, bD0);
    gl2lds16(bS + 64 * KK + k0, bD1);
    __syncthreads();                  // vmcnt(0) drain + all waves staged

    bf16x8 af[4], bf[4];
#pragma unroll
    for (int i = 0; i < 4; ++i)
      af[i] = *(const bf16x8*)(As + (wm * 64 + i * 16 + mrow) * 32 + kq);
#pragma unroll
    for (int j = 0; j < 4; ++j)
      bf[j] = *(const bf16x8*)(Bs + (wn * 64 + j * 16 + mrow) * 32 + kq);
#pragma unroll
    for (int i = 0; i < 4; ++i)
#pragma unroll
      for (int j = 0; j < 4; ++j)
        acc[i][j] = __builtin_amdgcn_mfma_f32_16x16x32_bf16(af[i], bf[j], acc[i][j], 0, 0, 0);
  }

  // Epilogue. C/D layout: col = lane&15, row = (lane>>4)*4 + reg.
  const int crow = (lane >> 4) * 4;
  const int ccol = lane & 15;
#pragma unroll
  for (int j = 0; j < 4; ++j) {
    int n = n0 + wn * 64 + j * 16 + ccol;
    float bv = bias_t[n];
    float* urow = u2 + ((size_t)n * 4 + b) * TP;
#pragma unroll
    for (int i = 0; i < 4; ++i) {
      int bt = t0 + wm * 64 + i * 16 + crow;   // mult of 4
      if (bt < TOUT) {
        f32x4 v = acc[i][j];
        v.x += bv; v.y += bv; v.z += bv; v.w += bv;
        *(f32x4*)(urow + bt) = v;              // may spill into pad [1953,1956)
      }
    }
  }
}

// ---------------------------------------------------------------------------
// Kernel 2: GLU (on load from u2) -> 1x1 share conv + leaky.
// br==1: store h_main; br==0: per-tile max over t -> gct_part.
__global__ __launch_bounds__(256) void share_act(
    const float* __restrict__ u2,
    const float* __restrict__ wsc, const float* __restrict__ bsc,
    const float* __restrict__ wsm, const float* __restrict__ bsm,
    float* __restrict__ hmain, float* __restrict__ gct_part) {
  __shared__ float Wl[128 * 132];   // Wl[cp*132 + cout] = ws[cout, cp]
  __shared__ float ul[128 * 68];    // ul[cp*68 + t]
  const int tid  = threadIdx.x;
  const int tile = blockIdx.x;      // 0..30
  const int b    = blockIdx.y;
  const int br   = blockIdx.z;
  const int t0   = tile * 64;
  const float* ws = br ? wsm : wsc;
  const float* bs = br ? bsm : bsc;

  for (int g = tid; g < 16384; g += 256) {
    int co = g >> 7, cp = g & 127;
    Wl[cp * 132 + co] = ws[g];
  }
  const size_t base_v = ((size_t)(br * 256) * 4 + b) * TP;
  const size_t base_g = ((size_t)(br * 256 + 128) * 4 + b) * TP;
  for (int g = tid; g < 8192; g += 256) {
    int cp = g >> 6, t = g & 63;
    float v = 0.f;
    if (t0 + t < TOUT) {
      float va = u2[base_v + (size_t)cp * 4 * TP + t0 + t];
      float vg = u2[base_g + (size_t)cp * 4 * TP + t0 + t];
      v = va * sigmoidf_(vg);
    }
    ul[cp * 68 + t] = v;
  }
  __syncthreads();

  const int ty = tid >> 4, tx = tid & 15;  // c-groups x t-groups
  float acc[8][4];
#pragma unroll
  for (int i = 0; i < 8; ++i)
#pragma unroll
    for (int j = 0; j < 4; ++j) acc[i][j] = 0.f;

  for (int cp = 0; cp < 128; ++cp) {
    float4 a0 = *(const float4*)&Wl[cp*132 + ty*4];
    float4 a1 = *(const float4*)&Wl[cp*132 + 64 + ty*4];
    float4 b4 = *(const float4*)&ul[cp*68 + tx*4];
    float av[8] = {a0.x,a0.y,a0.z,a0.w,a1.x,a1.y,a1.z,a1.w};
    float bv[4] = {b4.x,b4.y,b4.z,b4.w};
#pragma unroll
    for (int i = 0; i < 8; ++i)
#pragma unroll
      for (int j = 0; j < 4; ++j) acc[i][j] = fmaf(av[i], bv[j], acc[i][j]);
  }

  float mloc[8];
#pragma unroll
  for (int i = 0; i < 8; ++i) mloc[i] = -INFINITY;
#pragma unroll
  for (int i = 0; i < 8; ++i) {
    int c = (i < 4) ? (ty*4 + i) : (64 + ty*4 + (i - 4));
    float bias = bs[c];
#pragma unroll
    for (int j = 0; j < 4; ++j) {
      int t = t0 + tx*4 + j;
      if (t >= TOUT) continue;
      float v = acc[i][j] + bias;
      v = (v >= 0.f) ? v : 0.01f * v;
      if (br == 1) {
        hmain[((size_t)b * 128 + c) * TOUT + t] = v;
      } else {
        mloc[i] = fmaxf(mloc[i], v);
      }
    }
  }
  if (br == 0) {
    __syncthreads();               // done reading ul; reuse as reduction buffer
    float* red = ul;               // 128*16 region
#pragma unroll
    for (int i = 0; i < 8; ++i) {
      int c = (i < 4) ? (ty*4 + i) : (64 + ty*4 + (i - 4));
      red[c * 16 + tx] = mloc[i];
    }
    __syncthreads();
    if (tid < 128) {
      float m = -INFINITY;
#pragma unroll
      for (int k = 0; k < 16; ++k) m = fmaxf(m, red[tid * 16 + k]);
      gct_part[((size_t)b * 128 + tid) * NT2 + tile] = m;
    }
  }
}

// ---------------------------------------------------------------------------
// Kernel 3: gct = max over tiles; q = tanh(gct @ Wp^T + bp). One block per b.
__global__ void gct_q(const float* __restrict__ gct_part, const float* __restrict__ wp,
                      const float* __restrict__ bp, float* __restrict__ q) {
  int b = blockIdx.x, tid = threadIdx.x;   // 128 threads
  __shared__ float g[128];
  float m = -INFINITY;
  for (int tl = 0; tl < NT2; ++tl) m = fmaxf(m, gct_part[((size_t)b * 128 + tid) * NT2 + tl]);
  g[tid] = m;
  __syncthreads();
  float s = bp[tid];
  for (int c = 0; c < 128; ++c) s = fmaf(g[c], wp[tid * 128 + c], s);
  q[b * 128 + tid] = tanhf(s);
}

// ---------------------------------------------------------------------------
// Kernel 4: gate[t] = sigmoid(sum_c h*q); out_part = per-tile max_t h*gate.
__global__ __launch_bounds__(256) void gate_max(
    const float* __restrict__ hmain, const float* __restrict__ q,
    float* __restrict__ out_part) {
  __shared__ float hl[128 * 68];
  __shared__ float ql[128];
  __shared__ float red[256];
  __shared__ float gl[64];
  int tid = threadIdx.x, tile = blockIdx.x, b = blockIdx.y;
  int t0 = tile * 64;
  for (int g = tid; g < 8192; g += 256) {
    int c = g >> 6, t = g & 63;
    hl[c * 68 + t] = (t0 + t < TOUT) ? hmain[((size_t)b * 128 + c) * TOUT + t0 + t] : 0.f;
  }
  if (tid < 128) ql[tid] = q[b * 128 + tid];
  __syncthreads();
  {
    int t = tid & 63, cy = tid >> 6;
    float s = 0.f;
#pragma unroll
    for (int cc = 0; cc < 32; ++cc) s = fmaf(hl[(cy * 32 + cc) * 68 + t], ql[cy * 32 + cc], s);
    red[cy * 64 + t] = s;
  }
  __syncthreads();
  if (tid < 64) {
    float s = red[tid] + red[64 + tid] + red[128 + tid] + red[192 + tid];
    gl[tid] = sigmoidf_(s);
  }
  __syncthreads();
  {
    int c = tid >> 1, th = tid & 1;
    float m = -INFINITY;
#pragma unroll
    for (int tt = 0; tt < 32; ++tt) {
      int t = th * 32 + tt;
      if (t0 + t < TOUT) m = fmaxf(m, hl[c * 68 + t] * gl[t]);
    }
    red[c * 2 + th] = m;
  }
  __syncthreads();
  if (tid < 128) out_part[((size_t)b * 128 + tid) * NT2 + tile] = fmaxf(red[tid * 2], red[tid * 2 + 1]);
}

// ---------------------------------------------------------------------------
// Kernel 5: final max over tiles -> d_out (B,C) row-major.
__global__ void final_max(const float* __restrict__ out_part, float* __restrict__ out) {
  int idx = blockIdx.x * 256 + threadIdx.x;
  if (idx < 512) {
    float m = -INFINITY;
    for (int tl = 0; tl < NT2; ++tl) m = fmaxf(m, out_part[(size_t)idx * NT2 + tl]);
    out[idx] = m;
  }
}

// ---------------------------------------------------------------------------
extern "C" void kernel_launch(void* const* d_in, const int* in_sizes, int n_in,
                              void* d_out, int out_size, void* d_ws, size_t ws_size,
                              hipStream_t stream) {
  const float* x      = (const float*)d_in[0];
  const float* ctx_w  = (const float*)d_in[1];
  const float* ctx_b  = (const float*)d_in[2];
  const float* ctx_sw = (const float*)d_in[3];
  const float* ctx_sb = (const float*)d_in[4];
  const float* main_w = (const float*)d_in[5];
  const float* main_b = (const float*)d_in[6];
  const float* main_sw= (const float*)d_in[7];
  const float* main_sb= (const float*)d_in[8];
  const float* gp_w   = (const float*)d_in[9];
  const float* gp_b   = (const float*)d_in[10];

  char* w = (char*)d_ws;
  __hip_bfloat16* xb  = (__hip_bfloat16*)(w);              // 4*2^23*2   = 67,108,864 B
  __hip_bfloat16* Wtb = (__hip_bfloat16*)(w + 67108864);   // 512*4096*2 =  4,194,304
  float* bias_t  = (float*)(w + 71303168);                 // 512*4
  float* u2      = (float*)(w + 71305216);                 // 512*4*TP*4 = 16,023,552
  float* hmain   = (float*)(w + 87328768);                 // 4*128*1953*4 = 3,999,744
  float* gct_part= (float*)(w + 91328512);                 // 4*128*31*4 = 63,488
  float* q       = (float*)(w + 91392000);                 // 512*4
  float* out_part= (float*)(w + 91394048);                 // 63,488

  convert_x<<<16384, 256, 0, stream>>>(x, xb);
  prep_w<<<NCH, 256, 0, stream>>>(ctx_w, ctx_b, main_w, main_b, Wtb, bias_t);
  mfma_gemm<<<dim3(4, 16, B_), 256, 0, stream>>>(xb, Wtb, bias_t, u2);
  share_act<<<dim3(NT2, B_, 2), 256, 0, stream>>>(u2, ctx_sw, ctx_sb, main_sw, main_sb,
                                                  hmain, gct_part);
  gct_q<<<B_, 128, 0, stream>>>(gct_part, gp_w, gp_b, q);
  gate_max<<<dim3(NT2, B_), 256, 0, stream>>>(hmain, q, out_part);
  final_max<<<2, 256, 0, stream>>>(out_part, (float*)d_out);
}